// Round 5
// baseline (520.327 us; speedup 1.0000x reference)
//
#include <hip/hip_runtime.h>
#include <hip/hip_bf16.h>
#include <stdint.h>

// ---------------------------------------------------------------------------
// QuantizedLinear: y = x @ (qweight * scale)^T + bias
//   x [8192,4096] f32, qweight [4096,4096] i32 (exact in bf16), out f32.
// bf16 MFMA GEMM, 256x256 tile, BK=64, 8 waves, 4-phase/K-tile schedule,
// counted vmcnt(6) once per K-tile, setprio (T5), XCD swizzle (T1).
// R5: 32x32x16 MFMA with corrected bank swizzle:
//   sw(row) = (row&7) ^ ((row>>2)&4); slot = chunk ^ sw(row)
// R4's slot=chunk^(row&7) left lanes i and i+16 (rows differing by 16,
// same row&7, same chunk) on the same bank column -> 2.5e7 conflicts.
// Folding row-bit-4 into slot-bit-2 gives 4 distinct slots across
// {i,i+16,i+32,i+48} and keeps every 8-lane group covering all 8 slots.
// ---------------------------------------------------------------------------

#define M_ 8192
#define N_ 4096
#define K_ 4096
#define NT   (K_ / 64)     // 64 K-tiles
#define NTm1 (NT - 1)
#define N8X  (M_ * K_ / 8)
#define N8W  (N_ * K_ / 8)

typedef __bf16 bf16x8 __attribute__((ext_vector_type(8)));
typedef float  f32x16 __attribute__((ext_vector_type(16)));

typedef __attribute__((address_space(1))) void gvoid_t;
typedef __attribute__((address_space(3))) void lvoid_t;

__device__ __forceinline__ void gload_lds16(const __bf16* g, __bf16* l) {
    __builtin_amdgcn_global_load_lds(
        (gvoid_t*)(uintptr_t)g,
        (lvoid_t*)(uint32_t)(uintptr_t)l, 16, 0, 0);
}

#define BAR()      asm volatile("s_barrier" ::: "memory")
#define VMCNT(n)   asm volatile("s_waitcnt vmcnt(" #n ")" ::: "memory")

// bank swizzle: row in [0,128), chunk/slot in [0,8)
__device__ __forceinline__ int swz8(int row) {
    return (row & 7) ^ ((row >> 2) & 4);
}

// --------------------------- fused conversion ------------------------------

__global__ __launch_bounds__(256) void k_cvt(const float* __restrict__ x,
                                             const int* __restrict__ q,
                                             __bf16* __restrict__ xb,
                                             __bf16* __restrict__ wb) {
    const int stride = gridDim.x * 256;
    const int total = N8X + N8W;
    for (int i = blockIdx.x * 256 + threadIdx.x; i < total; i += stride) {
        if (i < N8X) {
            float4 a = ((const float4*)x)[(size_t)i * 2];
            float4 b = ((const float4*)x)[(size_t)i * 2 + 1];
            bf16x8 r;
            r[0] = (__bf16)a.x; r[1] = (__bf16)a.y; r[2] = (__bf16)a.z; r[3] = (__bf16)a.w;
            r[4] = (__bf16)b.x; r[5] = (__bf16)b.y; r[6] = (__bf16)b.z; r[7] = (__bf16)b.w;
            ((bf16x8*)xb)[i] = r;
        } else {
            const int j = i - N8X;
            int4 a = ((const int4*)q)[(size_t)j * 2];
            int4 b = ((const int4*)q)[(size_t)j * 2 + 1];
            bf16x8 r;
            r[0] = (__bf16)(float)a.x; r[1] = (__bf16)(float)a.y;
            r[2] = (__bf16)(float)a.z; r[3] = (__bf16)(float)a.w;
            r[4] = (__bf16)(float)b.x; r[5] = (__bf16)(float)b.y;
            r[6] = (__bf16)(float)b.z; r[7] = (__bf16)(float)b.w;
            ((bf16x8*)wb)[j] = r;
        }
    }
}

// ------------------------------- GEMM kernel -------------------------------
// LDS (bf16 elems): A slot (d,h) at (d*2+h)*8192; B at 32768 + same.
// Half-tile = 128 rows x 64 k. Storage: 16B-chunk c of row r lives at
// slot c ^ swz8(r). Stage ledger (R3-verified):
//   ph0: A[d^1][1] <- k+1 ; ph1: A[d][0] <- k+2 ; ph2: B[d][0] <- k+2
//   ph3: B[d][1] <- k+2, then vmcnt(6) => K-tile k+1 fully resident.
// MFMA: 32x32x16 bf16; per wave 4 m-tiles (mh,mq) x 2 n-tiles (nh).
//   A/B frag: row = lane&31 (+tile base), k-chunk = ks*2 + (lane>>5)
//   C/D: col = lane&31, row = (reg&3) + 8*(reg>>2) + 4*(lane>>5)  [m74/m101]

__global__ __launch_bounds__(512, 2)
void k_gemm(const __bf16* __restrict__ A, const __bf16* __restrict__ B,
            const float* __restrict__ scale, const float* __restrict__ bias,
            float* __restrict__ C) {
    __shared__ __bf16 sm[65536];   // 128 KiB

    const int tid  = threadIdx.x;
    const int lane = tid & 63;
    const int wave = tid >> 6;
    const int wr   = wave >> 2;       // 0..1
    const int wc   = wave & 3;        // 0..3
    const int l31  = lane & 31;
    const int hi   = lane >> 5;       // 0..1

    // T1: XCD-chunked bijective swizzle (512 wgs, 512%8==0)
    const int wg   = blockIdx.x;
    const int swz  = (wg & 7) * 64 + (wg >> 3);
    const int row0 = (swz >> 4) * 256;
    const int col0 = (swz & 15) * 256;

    __bf16* smA = sm;
    __bf16* smB = sm + 32768;

    f32x16 acc[2][2][2];   // [mh][mq][nh]
#pragma unroll
    for (int a = 0; a < 2; ++a)
#pragma unroll
        for (int b = 0; b < 2; ++b)
#pragma unroll
            for (int c = 0; c < 2; ++c)
#pragma unroll
                for (int r = 0; r < 16; ++r) acc[a][b][c][r] = 0.f;

    // staging: chunk q (0..1023) -> LDS elem q*8 (linear dest).
    // logical (row=q>>3, slot=q&7); global 16B chunk = slot ^ swz8(row).
    const int q0 = tid, q1 = tid + 512;
    const int r0 = q0 >> 3, s0 = q0 & 7;
    const int r1 = q1 >> 3, s1 = q1 & 7;
    const int c0 = (s0 ^ swz8(r0)) * 8;
    const int c1 = (s1 ^ swz8(r1)) * 8;
    const __bf16* a00 = A + (size_t)(row0 +       r0) * K_ + c0;
    const __bf16* a01 = A + (size_t)(row0 +       r1) * K_ + c1;
    const __bf16* a10 = A + (size_t)(row0 + 128 + r0) * K_ + c0;
    const __bf16* a11 = A + (size_t)(row0 + 128 + r1) * K_ + c1;
    const __bf16* b00 = B + (size_t)(col0 +       r0) * K_ + c0;
    const __bf16* b01 = B + (size_t)(col0 +       r1) * K_ + c1;
    const __bf16* b10 = B + (size_t)(col0 + 128 + r0) * K_ + c0;
    const __bf16* b11 = B + (size_t)(col0 + 128 + r1) * K_ + c1;
    const int la0 = q0 * 8, la1 = q1 * 8;

    auto stageA = [&](int d, int h, int kt) {
        __bf16* dst = smA + (d * 2 + h) * 8192;
        gload_lds16((h ? a10 : a00) + kt * 64, dst + la0);
        gload_lds16((h ? a11 : a01) + kt * 64, dst + la1);
    };
    auto stageB = [&](int d, int h, int kt) {
        __bf16* dst = smB + (d * 2 + h) * 8192;
        gload_lds16((h ? b10 : b00) + kt * 64, dst + la0);
        gload_lds16((h ? b11 : b01) + kt * 64, dst + la1);
    };
    // frag reads: chunk = ks*2 + hi, stored at slot chunk ^ swz8(row)
    auto rdA = [&](int d, int mh, int mq, int ks) -> bf16x8 {
        const int mrow = wr * 64 + mq * 32 + l31;
        const int off = (d * 2 + mh) * 8192 + mrow * 64
                      + (((ks * 2 + hi) ^ swz8(mrow)) * 8);
        return *(const bf16x8*)(smA + off);
    };
    auto rdB = [&](int d, int nh, int ks) -> bf16x8 {
        const int nrow = wc * 32 + l31;
        const int off = (d * 2 + nh) * 8192 + nrow * 64
                      + (((ks * 2 + hi) ^ swz8(nrow)) * 8);
        return *(const bf16x8*)(smB + off);
    };
    auto MF = [&](bf16x8 a, bf16x8 b, f32x16 c) -> f32x16 {
        return __builtin_amdgcn_mfma_f32_32x32x16_bf16(a, b, c, 0, 0, 0);
    };

    // prologue: K-tile 0 complete, then A0,B0,B1 of K-tile 1; vmcnt(6).
    stageA(0, 0, 0); stageB(0, 0, 0); stageB(0, 1, 0); stageA(0, 1, 0);
    stageA(1, 0, 1); stageB(1, 0, 1); stageB(1, 1, 1);
    VMCNT(6);
    BAR();

    bf16x8 af[2][4];   // A frags of current half [mq][ks]
    bf16x8 bf0[4];     // B half0 [ks]
    bf16x8 bf1[4];     // B half1

#pragma unroll 2
    for (int k = 0; k < NT; ++k) {
        const int d   = k & 1;
        const int e   = d ^ 1;
        const int kt1 = (k + 1 <= NTm1) ? k + 1 : NTm1;
        const int kt2 = (k + 2 <= NTm1) ? k + 2 : NTm1;

        // ---- phase 0: (mh0, nh0) — reads A-h0 (8) + B-h0 (4)
#pragma unroll
        for (int mq = 0; mq < 2; ++mq)
#pragma unroll
            for (int ks = 0; ks < 4; ++ks) af[mq][ks] = rdA(d, 0, mq, ks);
#pragma unroll
        for (int ks = 0; ks < 4; ++ks) bf0[ks] = rdB(d, 0, ks);
        stageA(e, 1, kt1);
        BAR();
        __builtin_amdgcn_s_setprio(1);
#pragma unroll
        for (int ks = 0; ks < 4; ++ks)
#pragma unroll
            for (int mq = 0; mq < 2; ++mq)
                acc[0][mq][0] = MF(af[mq][ks], bf0[ks], acc[0][mq][0]);
        __builtin_amdgcn_s_setprio(0);
        BAR();

        // ---- phase 1: (mh0, nh1) — reads B-h1 (4), A frags held
#pragma unroll
        for (int ks = 0; ks < 4; ++ks) bf1[ks] = rdB(d, 1, ks);
        stageA(d, 0, kt2);
        BAR();
        __builtin_amdgcn_s_setprio(1);
#pragma unroll
        for (int ks = 0; ks < 4; ++ks)
#pragma unroll
            for (int mq = 0; mq < 2; ++mq)
                acc[0][mq][1] = MF(af[mq][ks], bf1[ks], acc[0][mq][1]);
        __builtin_amdgcn_s_setprio(0);
        BAR();

        // ---- phase 2: (mh1, nh0) — reads A-h1 (8), B frags held
#pragma unroll
        for (int mq = 0; mq < 2; ++mq)
#pragma unroll
            for (int ks = 0; ks < 4; ++ks) af[mq][ks] = rdA(d, 1, mq, ks);
        stageB(d, 0, kt2);
        BAR();
        __builtin_amdgcn_s_setprio(1);
#pragma unroll
        for (int ks = 0; ks < 4; ++ks)
#pragma unroll
            for (int mq = 0; mq < 2; ++mq)
                acc[1][mq][0] = MF(af[mq][ks], bf0[ks], acc[1][mq][0]);
        __builtin_amdgcn_s_setprio(0);
        BAR();

        // ---- phase 3: (mh1, nh1) — no LDS reads
        stageB(d, 1, kt2);
        VMCNT(6);                      // K-tile k+1 fully resident
        BAR();
        __builtin_amdgcn_s_setprio(1);
#pragma unroll
        for (int ks = 0; ks < 4; ++ks)
#pragma unroll
            for (int mq = 0; mq < 2; ++mq)
                acc[1][mq][1] = MF(af[mq][ks], bf1[ks], acc[1][mq][1]);
        __builtin_amdgcn_s_setprio(0);
        BAR();
    }

    VMCNT(0);

    // epilogue: 32x32 C/D map col=lane&31, row=(r&3)+8*(r>>2)+4*hi (m74/m101)
    const float s = scale[0];
#pragma unroll
    for (int nh = 0; nh < 2; ++nh) {
        const int gc = col0 + nh * 128 + wc * 32 + l31;
        const float bv = bias[gc];
#pragma unroll
        for (int mh = 0; mh < 2; ++mh)
#pragma unroll
            for (int mq = 0; mq < 2; ++mq) {
                const int gr0 = row0 + mh * 128 + wr * 64 + mq * 32 + 4 * hi;
                const f32x16 v = acc[mh][mq][nh];
#pragma unroll
                for (int r = 0; r < 16; ++r) {
                    const int row = (r & 3) + 8 * (r >> 2);
                    C[(size_t)(gr0 + row) * N_ + gc] = v[r] * s + bv;
                }
            }
    }
}

// ------------------------------- launcher ----------------------------------

extern "C" void kernel_launch(void* const* d_in, const int* in_sizes, int n_in,
                              void* d_out, int out_size, void* d_ws, size_t ws_size,
                              hipStream_t stream) {
    const float* x     = (const float*)d_in[0];
    const int*   qw    = (const int*)d_in[1];
    const float* scale = (const float*)d_in[2];
    const float* bias  = (const float*)d_in[3];
    float*       out   = (float*)d_out;

    __bf16* xb = (__bf16*)d_ws;
    __bf16* wb = (__bf16*)((char*)d_ws + (size_t)M_ * K_ * sizeof(__bf16));

    k_cvt<<<2048, 256, 0, stream>>>(x, qw, xb, wb);
    k_gemm<<<512, 512, 0, stream>>>(xb, wb, scale, bias, out);
}

// Round 6
// 477.580 us; speedup vs baseline: 1.0895x; 1.0895x over previous
//
#include <hip/hip_runtime.h>
#include <hip/hip_bf16.h>
#include <stdint.h>

// ---------------------------------------------------------------------------
// QuantizedLinear: y = x @ (qweight * scale)^T + bias
//   x [8192,4096] f32, qweight [4096,4096] i32 (exact in bf16), out f32.
// R6: R3 configuration (16x16x32 MFMA, 0-conflict swizzle, 256x256 tile,
// BK=64, 8 waves, vmcnt(6) ledger, setprio, T1) with the barrier count
// HALVED: one s_barrier per phase (post-MFMA), vmcnt(6) after ph3's MFMA.
//
// Safety ledger for 1-barrier/phase (all post-MFMA):
//   - read->overwrite: slot read at phase p is CONSUMED by p's MFMA (compiler
//     lgkmcnt drains the ds_read before use), which precedes p's barrier.
//     The overwriting stage is issued at phase >= p+1, i.e. after that
//     barrier -> after consumption. No in-flight-read vs write race.
//   - stage->read: reads of K-tile k+1 (ph0 of k+1) happen after ph3(k)'s
//     vmcnt(6)+BAR; vmcnt(6) retires every stage up to and including
//     ph0(k)'s A(e,1)<-k+1, i.e. all four half-tiles of k+1. BAR after the
//     vmcnt publishes them to all waves.
//   - register reuse (bf0 in ph2, af/bf1 in ph3) is per-wave in-order: safe.
// ---------------------------------------------------------------------------

#define M_ 8192
#define N_ 4096
#define K_ 4096
#define NT   (K_ / 64)     // 64 K-tiles
#define NTm1 (NT - 1)
#define N8X  (M_ * K_ / 8)
#define N8W  (N_ * K_ / 8)

typedef __bf16 bf16x8 __attribute__((ext_vector_type(8)));
typedef float  f32x4  __attribute__((ext_vector_type(4)));

typedef __attribute__((address_space(1))) void gvoid_t;
typedef __attribute__((address_space(3))) void lvoid_t;

__device__ __forceinline__ void gload_lds16(const __bf16* g, __bf16* l) {
    __builtin_amdgcn_global_load_lds(
        (gvoid_t*)(uintptr_t)g,
        (lvoid_t*)(uint32_t)(uintptr_t)l, 16, 0, 0);
}

#define BAR()      asm volatile("s_barrier" ::: "memory")
#define VMCNT(n)   asm volatile("s_waitcnt vmcnt(" #n ")" ::: "memory")

// --------------------------- fused conversion ------------------------------

__global__ __launch_bounds__(256) void k_cvt(const float* __restrict__ x,
                                             const int* __restrict__ q,
                                             __bf16* __restrict__ xb,
                                             __bf16* __restrict__ wb) {
    const int stride = gridDim.x * 256;
    const int total = N8X + N8W;
    for (int i = blockIdx.x * 256 + threadIdx.x; i < total; i += stride) {
        if (i < N8X) {
            float4 a = ((const float4*)x)[(size_t)i * 2];
            float4 b = ((const float4*)x)[(size_t)i * 2 + 1];
            bf16x8 r;
            r[0] = (__bf16)a.x; r[1] = (__bf16)a.y; r[2] = (__bf16)a.z; r[3] = (__bf16)a.w;
            r[4] = (__bf16)b.x; r[5] = (__bf16)b.y; r[6] = (__bf16)b.z; r[7] = (__bf16)b.w;
            ((bf16x8*)xb)[i] = r;
        } else {
            const int j = i - N8X;
            int4 a = ((const int4*)q)[(size_t)j * 2];
            int4 b = ((const int4*)q)[(size_t)j * 2 + 1];
            bf16x8 r;
            r[0] = (__bf16)(float)a.x; r[1] = (__bf16)(float)a.y;
            r[2] = (__bf16)(float)a.z; r[3] = (__bf16)(float)a.w;
            r[4] = (__bf16)(float)b.x; r[5] = (__bf16)(float)b.y;
            r[6] = (__bf16)(float)b.z; r[7] = (__bf16)(float)b.w;
            ((bf16x8*)wb)[j] = r;
        }
    }
}

// ------------------------------- GEMM kernel -------------------------------
// LDS (bf16 elems): A slot (d,h) at (d*2+h)*8192; B at 32768 + same.
// Half-tile = 128 rows x 64 k. Storage: 16B-chunk c of row r at slot
// c ^ (r&7) (R3 swizzle, measured 0 conflicts with the 16x16 read pattern).
// Stage ledger: ph0: A[d^1][1]<-k+1 ; ph1: A[d][0]<-k+2 ; ph2: B[d][0]<-k+2 ;
// ph3: B[d][1]<-k+2 then MFMA then vmcnt(6) then BAR.
// MFMA 16x16x32: A/B frag row = lane&15, k-chunk = kk*4 + (lane>>4).
// C/D: col = lane&15, row = (lane>>4)*4 + j  [m89-verified]

__global__ __launch_bounds__(512, 2)
void k_gemm(const __bf16* __restrict__ A, const __bf16* __restrict__ B,
            const float* __restrict__ scale, const float* __restrict__ bias,
            float* __restrict__ C) {
    __shared__ __bf16 sm[65536];   // 128 KiB

    const int tid  = threadIdx.x;
    const int lane = tid & 63;
    const int wave = tid >> 6;
    const int wr   = wave >> 2;       // 0..1
    const int wc   = wave & 3;        // 0..3
    const int lr   = lane & 15;
    const int lg   = lane >> 4;       // 0..3

    // T1: XCD-chunked bijective swizzle (512 wgs, 512%8==0)
    const int wg   = blockIdx.x;
    const int swz  = (wg & 7) * 64 + (wg >> 3);
    const int row0 = (swz >> 4) * 256;
    const int col0 = (swz & 15) * 256;

    __bf16* smA = sm;
    __bf16* smB = sm + 32768;

    f32x4 acc[8][4];
#pragma unroll
    for (int m = 0; m < 8; ++m)
#pragma unroll
        for (int n = 0; n < 4; ++n) acc[m][n] = (f32x4){0.f, 0.f, 0.f, 0.f};

    // staging: chunk q (0..1023) -> LDS elem q*8 (linear dest).
    // logical (row=q>>3, slot=q&7); global 16B chunk = slot ^ (row&7).
    const int q0 = tid, q1 = tid + 512;
    const int r0 = q0 >> 3, s0 = q0 & 7;
    const int r1 = q1 >> 3, s1 = q1 & 7;
    const int c0 = (s0 ^ (r0 & 7)) * 8;
    const int c1 = (s1 ^ (r1 & 7)) * 8;
    const __bf16* a00 = A + (size_t)(row0 +       r0) * K_ + c0;
    const __bf16* a01 = A + (size_t)(row0 +       r1) * K_ + c1;
    const __bf16* a10 = A + (size_t)(row0 + 128 + r0) * K_ + c0;
    const __bf16* a11 = A + (size_t)(row0 + 128 + r1) * K_ + c1;
    const __bf16* b00 = B + (size_t)(col0 +       r0) * K_ + c0;
    const __bf16* b01 = B + (size_t)(col0 +       r1) * K_ + c1;
    const __bf16* b10 = B + (size_t)(col0 + 128 + r0) * K_ + c0;
    const __bf16* b11 = B + (size_t)(col0 + 128 + r1) * K_ + c1;
    const int la0 = q0 * 8, la1 = q1 * 8;

    auto stageA = [&](int d, int h, int kt) {
        __bf16* dst = smA + (d * 2 + h) * 8192;
        gload_lds16((h ? a10 : a00) + kt * 64, dst + la0);
        gload_lds16((h ? a11 : a01) + kt * 64, dst + la1);
    };
    auto stageB = [&](int d, int h, int kt) {
        __bf16* dst = smB + (d * 2 + h) * 8192;
        gload_lds16((h ? b10 : b00) + kt * 64, dst + la0);
        gload_lds16((h ? b11 : b01) + kt * 64, dst + la1);
    };
    // frag reads: chunk = kk*4 + lg, stored at slot chunk ^ (row&7)
    auto rdA = [&](int d, int mh, int m16, int kk) -> bf16x8 {
        const int mrow = wr * 64 + m16 * 16 + lr;
        const int off = (d * 2 + mh) * 8192 + mrow * 64
                      + (((kk * 4 + lg) ^ (mrow & 7)) * 8);
        return *(const bf16x8*)(smA + off);
    };
    auto rdB = [&](int d, int nh, int n16, int kk) -> bf16x8 {
        const int nrow = wc * 32 + n16 * 16 + lr;
        const int off = (d * 2 + nh) * 8192 + nrow * 64
                      + (((kk * 4 + lg) ^ (nrow & 7)) * 8);
        return *(const bf16x8*)(smB + off);
    };
    auto MF = [&](bf16x8 a, bf16x8 b, f32x4 c) -> f32x4 {
        return __builtin_amdgcn_mfma_f32_16x16x32_bf16(a, b, c, 0, 0, 0);
    };

    // prologue: K-tile 0 complete, then A0,B0,B1 of K-tile 1; vmcnt(6)
    // retires the first 4 stages (= all of K-tile 0).
    stageA(0, 0, 0); stageB(0, 0, 0); stageB(0, 1, 0); stageA(0, 1, 0);
    stageA(1, 0, 1); stageB(1, 0, 1); stageB(1, 1, 1);
    VMCNT(6);
    BAR();

    bf16x8 af[4][2];   // A frags of current half [m16][kk]
    bf16x8 bf0[2][2];  // B half0 [n16][kk]
    bf16x8 bf1[2][2];  // B half1

#pragma unroll 2
    for (int k = 0; k < NT; ++k) {
        const int d   = k & 1;
        const int e   = d ^ 1;
        const int kt1 = (k + 1 <= NTm1) ? k + 1 : NTm1;   // clamp -> dead slot
        const int kt2 = (k + 2 <= NTm1) ? k + 2 : NTm1;   // clamp -> dead slot

        // ---- phase 0: quadrant (0,0) — reads A-h0 (8) + B-h0 (4)
#pragma unroll
        for (int m = 0; m < 4; ++m)
#pragma unroll
            for (int kk = 0; kk < 2; ++kk) af[m][kk] = rdA(d, 0, m, kk);
#pragma unroll
        for (int n = 0; n < 2; ++n)
#pragma unroll
            for (int kk = 0; kk < 2; ++kk) bf0[n][kk] = rdB(d, 0, n, kk);
        stageA(e, 1, kt1);
        __builtin_amdgcn_s_setprio(1);
#pragma unroll
        for (int kk = 0; kk < 2; ++kk)
#pragma unroll
            for (int m = 0; m < 4; ++m)
#pragma unroll
                for (int n = 0; n < 2; ++n)
                    acc[m][n] = MF(af[m][kk], bf0[n][kk], acc[m][n]);
        __builtin_amdgcn_s_setprio(0);
        BAR();

        // ---- phase 1: quadrant (0,1) — reads B-h1 (4); A frags held
#pragma unroll
        for (int n = 0; n < 2; ++n)
#pragma unroll
            for (int kk = 0; kk < 2; ++kk) bf1[n][kk] = rdB(d, 1, n, kk);
        stageA(d, 0, kt2);
        __builtin_amdgcn_s_setprio(1);
#pragma unroll
        for (int kk = 0; kk < 2; ++kk)
#pragma unroll
            for (int m = 0; m < 4; ++m)
#pragma unroll
                for (int n = 0; n < 2; ++n)
                    acc[m][2 + n] = MF(af[m][kk], bf1[n][kk], acc[m][2 + n]);
        __builtin_amdgcn_s_setprio(0);
        BAR();

        // ---- phase 2: quadrant (1,0) — reads A-h1 (8); B0 frags held
#pragma unroll
        for (int m = 0; m < 4; ++m)
#pragma unroll
            for (int kk = 0; kk < 2; ++kk) af[m][kk] = rdA(d, 1, m, kk);
        stageB(d, 0, kt2);
        __builtin_amdgcn_s_setprio(1);
#pragma unroll
        for (int kk = 0; kk < 2; ++kk)
#pragma unroll
            for (int m = 0; m < 4; ++m)
#pragma unroll
                for (int n = 0; n < 2; ++n)
                    acc[4 + m][n] = MF(af[m][kk], bf0[n][kk], acc[4 + m][n]);
        __builtin_amdgcn_s_setprio(0);
        BAR();

        // ---- phase 3: quadrant (1,1) — no LDS reads; A1,B1 frags held
        stageB(d, 1, kt2);
        __builtin_amdgcn_s_setprio(1);
#pragma unroll
        for (int kk = 0; kk < 2; ++kk)
#pragma unroll
            for (int m = 0; m < 4; ++m)
#pragma unroll
                for (int n = 0; n < 2; ++n)
                    acc[4 + m][2 + n] = MF(af[m][kk], bf1[n][kk], acc[4 + m][2 + n]);
        __builtin_amdgcn_s_setprio(0);
        VMCNT(6);                      // K-tile k+1 fully resident (after MFMA
        BAR();                         // so the vmem wait overlaps compute)
    }

    VMCNT(0);

    // epilogue: frag C/D layout col=lane&15, row=lg*4+j (m89-verified)
    const float s = scale[0];
#pragma unroll
    for (int nh = 0; nh < 2; ++nh)
#pragma unroll
        for (int n16 = 0; n16 < 2; ++n16) {
            const int gc = col0 + nh * 128 + wc * 32 + n16 * 16 + lr;
            const float bv = bias[gc];
#pragma unroll
            for (int mh = 0; mh < 2; ++mh)
#pragma unroll
                for (int m16 = 0; m16 < 4; ++m16) {
                    const int gr = row0 + mh * 128 + wr * 64 + m16 * 16 + lg * 4;
                    const f32x4 v = acc[mh * 4 + m16][nh * 2 + n16];
#pragma unroll
                    for (int j = 0; j < 4; ++j)
                        C[(size_t)(gr + j) * N_ + gc] = v[j] * s + bv;
                }
        }
}

// ------------------------------- launcher ----------------------------------

extern "C" void kernel_launch(void* const* d_in, const int* in_sizes, int n_in,
                              void* d_out, int out_size, void* d_ws, size_t ws_size,
                              hipStream_t stream) {
    const float* x     = (const float*)d_in[0];
    const int*   qw    = (const int*)d_in[1];
    const float* scale = (const float*)d_in[2];
    const float* bias  = (const float*)d_in[3];
    float*       out   = (float*)d_out;

    __bf16* xb = (__bf16*)d_ws;
    __bf16* wb = (__bf16*)((char*)d_ws + (size_t)M_ * K_ * sizeof(__bf16));

    k_cvt<<<2048, 256, 0, stream>>>(x, qw, xb, wb);
    k_gemm<<<512, 512, 0, stream>>>(xb, wb, scale, bias, out);
}